// Round 6
// baseline (814.925 us; speedup 1.0000x reference)
//
#include <hip/hip_runtime.h>

#define CIN   64
#define COUT  64
#define HID   32
#define ZD    128
#define KC    1024
#define SPC   64
#define TLEN  65536

typedef __attribute__((ext_vector_type(8))) short bf16x8;
typedef __attribute__((ext_vector_type(4))) float f32x4;

__device__ __forceinline__ unsigned f2bf(float f) {
    unsigned u = __float_as_uint(f);
    unsigned r = u + 0x7fffu + ((u >> 16) & 1u);
    return r >> 16;
}
__device__ __forceinline__ unsigned pk2(float a, float b) {
    return f2bf(a) | (f2bf(b) << 16);
}

// w2 [8192 r][32 h] fp32 -> w2b [8192 r][16 packed bf16x2]  (B-fragment friendly)
__global__ void cast_w2_kernel(const float* __restrict__ w2, unsigned* __restrict__ w2b) {
    int i  = blockIdx.x * 256 + threadIdx.x;   // 131072
    int r  = i >> 4;
    int hp = i & 15;
    w2b[i] = pk2(w2[r * HID + 2 * hp], w2[r * HID + 2 * hp + 1]);
}

// x [B][CIN][T] fp32 -> xT [B][T][CIN] bf16 (tiled transpose through LDS)
__global__ __launch_bounds__(256)
void transpose_cast_x(const float* __restrict__ x, unsigned short* __restrict__ xT) {
    __shared__ unsigned short s[64][66];   // stride 66 shorts: conflict-free writes
    const int blk  = blockIdx.x;           // 8192 = B * T/64
    const int b    = blk >> 10;
    const int t0   = (blk & 1023) << 6;
    const int lane = threadIdx.x & 63;
    const int wv   = threadIdx.x >> 6;
    const float* xb = x + (size_t)b * CIN * TLEN;
    #pragma unroll
    for (int cc = 0; cc < 16; ++cc) {
        int c = cc * 4 + wv;
        s[lane][c] = (unsigned short)f2bf(xb[(size_t)c * TLEN + t0 + lane]);
    }
    __syncthreads();
    unsigned short* ob = xT + ((size_t)b * TLEN + t0) * CIN;
    #pragma unroll
    for (int half = 0; half < 2; ++half) {
        int si = (half * 256 + threadIdx.x) * 8;   // short index in 64x64 tile
        int t = si >> 6, c = si & 63;              // c multiple of 8 -> 4B-aligned LDS reads
        const unsigned* sp = (const unsigned*)&s[t][c];
        uint4 v; v.x = sp[0]; v.y = sp[1]; v.z = sp[2]; v.w = sp[3];
        *(uint4*)&ob[(size_t)t * CIN + c] = v;     // fully coalesced 16B/lane
    }
}

// ---------- Path 1: de-fused (needs ~204 MB workspace) ----------

// W-gen, full-rank: block = 16 samples x 2048 r (one ks-slice).
// A rows = 16 DISTINCT samples -> every MFMA output element is useful.
__global__ __launch_bounds__(256, 4)
void wgen16_kernel(const float* __restrict__ z,
                   const float* __restrict__ w1, const float* __restrict__ b1,
                   const float* __restrict__ b2,
                   const float* __restrict__ w3, const float* __restrict__ b3,
                   const float* __restrict__ w4, const float* __restrict__ b4,
                   const uint4* __restrict__ w2b,
                   unsigned short* __restrict__ Wg, float* __restrict__ biasg)
{
    __shared__ __align__(16) float s_z[16][ZD];     // 8 KB
    __shared__ __align__(16) float s_h3[16][HID];   // 2 KB
    __shared__ __align__(16) short s_h1b[16][40];   // padded stride (bank spread), 1.25 KB

    const int tid  = threadIdx.x;
    const int w    = tid >> 6;
    const int lane = tid & 63;
    const int l15  = lane & 15;
    const int q    = lane >> 4;
    const int blk  = blockIdx.x;          // 2048 = 512 sample-groups x 4 ks
    const int ksr  = blk & 3;
    const int smp0 = (blk >> 2) * 16;
    const int b    = smp0 >> 10;
    const int kk0  = smp0 & 1023;         // multiple of 16

    // ---- stage z[b, :, kk0..kk0+15] (float4 over the k-dim, transpose into [g][d]) ----
    #pragma unroll
    for (int rep = 0; rep < 2; ++rep) {
        int idx = tid + rep * 256;        // 512 float4 slots
        int d = idx >> 2, g4 = idx & 3;
        float4 v = *(const float4*)&z[((size_t)b * ZD + d) * KC + kk0 + g4 * 4];
        s_z[g4 * 4 + 0][d] = v.x;
        s_z[g4 * 4 + 1][d] = v.y;
        s_z[g4 * 4 + 2][d] = v.z;
        s_z[g4 * 4 + 3][d] = v.w;
    }
    __syncthreads();

    // ---- h1 (bf16) and h3 for 16 samples: thread = (unit u, sample-group g0+4gg) ----
    {
        int u  = tid & 63;
        int g0 = tid >> 6;                // 0..3
        const float* wrow = (u < HID) ? (w1 + u * ZD) : (w3 + (u - HID) * ZD);
        float bb = (u < HID) ? b1[u] : b3[u - HID];
        float acc4[4] = {bb, bb, bb, bb};
        #pragma unroll
        for (int d4 = 0; d4 < ZD / 4; ++d4) {
            float4 wv = *(const float4*)(wrow + 4 * d4);
            #pragma unroll
            for (int gg = 0; gg < 4; ++gg) {
                float4 zv = *(const float4*)(&s_z[g0 + 4 * gg][4 * d4]);
                acc4[gg] += wv.x * zv.x + wv.y * zv.y + wv.z * zv.z + wv.w * zv.w;
            }
        }
        #pragma unroll
        for (int gg = 0; gg < 4; ++gg) {
            int g = g0 + 4 * gg;
            float a = fmaxf(acc4[gg], 0.f);
            if (u < HID) s_h1b[g][u] = (short)f2bf(a);
            else         s_h3[g][u - HID] = a;
        }
    }
    __syncthreads();

    // ---- bias (only the ksr==0 block writes it) ----
    if (ksr == 0) {
        int o  = tid & 63;
        int g0 = tid >> 6;
        float bb = b4[o];
        float acc4[4] = {bb, bb, bb, bb};
        #pragma unroll
        for (int h4 = 0; h4 < HID / 4; ++h4) {
            float4 wv = *(const float4*)(w4 + o * HID + 4 * h4);
            #pragma unroll
            for (int gg = 0; gg < 4; ++gg) {
                float4 hv = *(const float4*)(&s_h3[g0 + 4 * gg][4 * h4]);
                acc4[gg] += wv.x * hv.x + wv.y * hv.y + wv.z * hv.z + wv.w * hv.w;
            }
        }
        #pragma unroll
        for (int gg = 0; gg < 4; ++gg)
            biasg[(size_t)(smp0 + g0 + 4 * gg) * COUT + o] = acc4[gg];
    }

    // ---- W tile: A[m=sample l15][k=h q*8+j]; B[k=h][n=r]; C rows 4q+reg = samples ----
    bf16x8 afrag = *(const bf16x8*)&s_h1b[l15][q * 8];
    const int rb = ksr * 2048 + w * 512;  // wave w owns 512 r within this ks-slice

    #pragma unroll
    for (int ntl = 0; ntl < 4; ++ntl) {
        f32x4 cj[8];
        #pragma unroll
        for (int jj = 0; jj < 8; ++jj) {
            int r = rb + 64 * jj + 16 * ntl + l15;
            float b2v = b2[r];
            bf16x8 bfrag = __builtin_bit_cast(bf16x8, w2b[r * 4 + q]);
            cj[jj] = __builtin_amdgcn_mfma_f32_16x16x32_bf16(
                afrag, bfrag, (f32x4){b2v, b2v, b2v, b2v}, 0, 0, 0);
        }
        const int i = 16 * ntl + l15;
        #pragma unroll
        for (int reg = 0; reg < 4; ++reg) {
            uint4 res;
            res.x = pk2(cj[0][reg], cj[1][reg]);
            res.y = pk2(cj[2][reg], cj[3][reg]);
            res.z = pk2(cj[4][reg], cj[5][reg]);
            res.w = pk2(cj[6][reg], cj[7][reg]);
            *(uint4*)&Wg[(size_t)(smp0 + 4 * q + reg) * 8192 + rb + i * 8] = res;
        }
    }
}

// Conv: barrier-free, LDS-free. Wave = (sample, o-half); acc[2][4] = 32 AGPRs.
__global__ __launch_bounds__(256, 5)
void hyperconv_apply(const unsigned short* __restrict__ xT,
                     const unsigned short* __restrict__ Wg,
                     const float* __restrict__ biasg,
                     float* __restrict__ out)
{
    const int tid  = threadIdx.x;
    const int w    = tid >> 6;
    const int lane = tid & 63;
    const int l15  = lane & 15;
    const int q    = lane >> 4;
    const int smp  = blockIdx.x * 2 + (w >> 1);   // 4096 blocks -> 8192 samples
    const int oh   = w & 1;                        // o-half 0/1
    const int b    = smp >> 10;
    const int t0   = (smp & 1023) * SPC;

    const unsigned short* xtb = xT + (size_t)b * TLEN * CIN;
    const unsigned short* Wn  = Wg + (size_t)smp * 8192;

    f32x4 acc[2][4];
    #pragma unroll
    for (int i = 0; i < 2; ++i)
        #pragma unroll
        for (int j = 0; j < 4; ++j) acc[i][j] = (f32x4){0.f, 0.f, 0.f, 0.f};

    #pragma unroll
    for (int ks = 0; ks < 4; ++ks) {
        const int koff = (ks >= 2) ? -1 : 0;   // ik>=64 -> x[t-1]
        const int c0   = (ks & 1) * 32 + 8 * q;
        bf16x8 bfr[4];
        #pragma unroll
        for (int st = 0; st < 4; ++st) {
            int t = t0 + 16 * st + l15 + koff;
            uint4 p = (uint4){0u, 0u, 0u, 0u};
            if (t >= 0) p = *(const uint4*)&xtb[(size_t)t * CIN + c0];
            bfr[st] = __builtin_bit_cast(bf16x8, p);
        }
        #pragma unroll
        for (int ot = 0; ot < 2; ++ot) {
            const int ot2 = oh * 2 + ot;
            bf16x8 afr = *(const bf16x8*)&Wn[ks * 2048 + q * 512 + (16 * ot2 + l15) * 8];
            #pragma unroll
            for (int st = 0; st < 4; ++st)
                acc[ot][st] = __builtin_amdgcn_mfma_f32_16x16x32_bf16(
                    afr, bfr[st], acc[ot][st], 0, 0, 0);
        }
    }

    const float* bn = biasg + (size_t)smp * COUT;
    float* ob = out + (size_t)b * COUT * TLEN;
    #pragma unroll
    for (int ot = 0; ot < 2; ++ot) {
        const int ot2 = oh * 2 + ot;
        f32x4 bv = *(const f32x4*)&bn[16 * ot2 + 4 * q];
        #pragma unroll
        for (int st = 0; st < 4; ++st) {
            int t = t0 + 16 * st + l15;
            #pragma unroll
            for (int reg = 0; reg < 4; ++reg)
                ob[(size_t)(16 * ot2 + 4 * q + reg) * TLEN + t] = acc[ot][st][reg] + bv[reg];
        }
    }
}

// ---------- Path 2: fused fallback (round-4 kernel, needs 67.6 MB / 0.5 MB) ----------

template<bool USE_XT>
__global__ __launch_bounds__(256, 2)
void hyperconv_mfma(const float* __restrict__ x, const unsigned short* __restrict__ xT,
                    const float* __restrict__ z,
                    const float* __restrict__ w1, const float* __restrict__ b1,
                    const float* __restrict__ b2,
                    const float* __restrict__ w3, const float* __restrict__ b3,
                    const float* __restrict__ w4, const float* __restrict__ b4,
                    const uint4* __restrict__ w2b,
                    float* __restrict__ out)
{
    __shared__ __align__(16) float s_z[4][ZD];
    __shared__ __align__(16) float s_h3[4][HID];
    __shared__ __align__(16) float s_bias[4][COUT];
    __shared__ __align__(16) short s_h1b[4][HID];
    __shared__ __align__(16) short s_wc[4][2048];

    const int tid  = threadIdx.x;
    const int w    = tid >> 6;
    const int lane = tid & 63;
    const int l15  = lane & 15;
    const int q    = lane >> 4;
    const int n0   = blockIdx.x * 4;
    const int b    = n0 >> 10;
    const int kk0  = n0 & 1023;

    #pragma unroll
    for (int i = 0; i < 2; ++i) {
        int idx = tid + i * 256;
        int g = idx >> 7, d = idx & 127;
        s_z[g][d] = z[((size_t)b * ZD + d) * KC + kk0 + g];
    }
    __syncthreads();

    {
        int g = tid >> 6, u = tid & 63;
        const float* wrow = (u < HID) ? (w1 + u * ZD) : (w3 + (u - HID) * ZD);
        float acc = (u < HID) ? b1[u] : b3[u - HID];
        #pragma unroll
        for (int d4 = 0; d4 < ZD / 4; ++d4) {
            float4 wv = *(const float4*)(wrow + 4 * d4);
            float4 zv = *(const float4*)(&s_z[g][4 * d4]);
            acc += wv.x * zv.x + wv.y * zv.y + wv.z * zv.z + wv.w * zv.w;
        }
        acc = fmaxf(acc, 0.f);
        if (u < HID) s_h1b[g][u] = (short)f2bf(acc);
        else         s_h3[g][u - HID] = acc;
    }
    __syncthreads();

    {
        int g = tid >> 6, o = tid & 63;
        float acc = b4[o];
        #pragma unroll
        for (int h4 = 0; h4 < HID / 4; ++h4) {
            float4 wv = *(const float4*)(w4 + o * HID + 4 * h4);
            float4 hv = *(const float4*)(&s_h3[g][4 * h4]);
            acc += wv.x * hv.x + wv.y * hv.y + wv.z * hv.z + wv.w * hv.w;
        }
        s_bias[g][o] = acc;
    }

    bf16x8 afrag = *(const bf16x8*)&s_h1b[l15 >> 2][q * 8];

    auto produce = [&](int ksr) {
        const int rb = ksr * 2048 + w * 512;
        #pragma unroll
        for (int ntl = 0; ntl < 4; ++ntl) {
            float cvq[8];
            #pragma unroll
            for (int jj = 0; jj < 8; ++jj) {
                int r = rb + 64 * jj + 16 * ntl + l15;
                float b2v = b2[r];
                bf16x8 bfrag = __builtin_bit_cast(bf16x8, w2b[r * 4 + q]);
                f32x4 c = __builtin_amdgcn_mfma_f32_16x16x32_bf16(
                    afrag, bfrag, (f32x4){b2v, b2v, b2v, b2v}, 0, 0, 0);
                cvq[jj] = c[0];
            }
            uint4 res;
            res.x = pk2(cvq[0], cvq[1]);
            res.y = pk2(cvq[2], cvq[3]);
            res.z = pk2(cvq[4], cvq[5]);
            res.w = pk2(cvq[6], cvq[7]);
            *(uint4*)&s_wc[q][w * 512 + (16 * ntl + l15) * 8] = res;
        }
    };

    produce(0);
    __syncthreads();

    const int t0 = (kk0 + w) * SPC;
    const float* xb = x + (size_t)b * CIN * TLEN;
    const unsigned short* xtb = xT + (size_t)b * TLEN * CIN;

    f32x4 acc[4][4];
    #pragma unroll
    for (int i = 0; i < 4; ++i)
        #pragma unroll
        for (int j = 0; j < 4; ++j) acc[i][j] = (f32x4){0.f, 0.f, 0.f, 0.f};

    #pragma unroll
    for (int ks = 0; ks < 4; ++ks) {
        const int koff = (ks >= 2) ? -1 : 0;
        const int c0 = (ks & 1) * 32 + 8 * q;
        bf16x8 bfr[4];
        if (USE_XT) {
            #pragma unroll
            for (int st = 0; st < 4; ++st) {
                int t = t0 + 16 * st + l15 + koff;
                uint4 p = (uint4){0u, 0u, 0u, 0u};
                if (t >= 0) p = *(const uint4*)&xtb[(size_t)t * CIN + c0];
                bfr[st] = __builtin_bit_cast(bf16x8, p);
            }
        } else {
            #pragma unroll
            for (int st = 0; st < 4; ++st) {
                int t = t0 + 16 * st + l15 + koff;
                int tc = t < 0 ? 0 : t;
                float v[8];
                #pragma unroll
                for (int j = 0; j < 8; ++j)
                    v[j] = xb[(size_t)(c0 + j) * TLEN + tc];
                if (t < 0) {
                    #pragma unroll
                    for (int j = 0; j < 8; ++j) v[j] = 0.f;
                }
                uint4 p;
                p.x = pk2(v[0], v[1]); p.y = pk2(v[2], v[3]);
                p.z = pk2(v[4], v[5]); p.w = pk2(v[6], v[7]);
                bfr[st] = __builtin_bit_cast(bf16x8, p);
            }
        }

        #pragma unroll
        for (int ot = 0; ot < 4; ++ot) {
            bf16x8 afr = *(const bf16x8*)&s_wc[w][q * 512 + (16 * ot + l15) * 8];
            #pragma unroll
            for (int st = 0; st < 4; ++st)
                acc[ot][st] = __builtin_amdgcn_mfma_f32_16x16x32_bf16(
                    afr, bfr[st], acc[ot][st], 0, 0, 0);
        }

        if (ks < 3) {
            __syncthreads();
            produce(ks + 1);
            __syncthreads();
        }
    }

    float* ob = out + (size_t)b * COUT * TLEN;
    #pragma unroll
    for (int ot = 0; ot < 4; ++ot) {
        f32x4 bv = *(const f32x4*)&s_bias[w][16 * ot + 4 * q];
        #pragma unroll
        for (int st = 0; st < 4; ++st) {
            int t = t0 + 16 * st + l15;
            #pragma unroll
            for (int reg = 0; reg < 4; ++reg)
                ob[(size_t)(16 * ot + 4 * q + reg) * TLEN + t] = acc[ot][st][reg] + bv[reg];
        }
    }
}

extern "C" void kernel_launch(void* const* d_in, const int* in_sizes, int n_in,
                              void* d_out, int out_size, void* d_ws, size_t ws_size,
                              hipStream_t stream) {
    const float* x  = (const float*)d_in[0];
    const float* z  = (const float*)d_in[1];
    const float* w1 = (const float*)d_in[2];
    const float* b1 = (const float*)d_in[3];
    const float* w2 = (const float*)d_in[4];
    const float* b2 = (const float*)d_in[5];
    const float* w3 = (const float*)d_in[6];
    const float* b3 = (const float*)d_in[7];
    const float* w4 = (const float*)d_in[8];
    const float* b4 = (const float*)d_in[9];
    float* out = (float*)d_out;

    const size_t off_xt   = 524288;                         // after w2b
    const size_t off_wg   = off_xt + 67108864;              // after xT (64 MB)
    const size_t off_bias = off_wg + 134217728;             // after Wg (128 MB)
    const size_t need_xt   = off_wg;                        // 67,633,152
    const size_t need_full = off_bias + 2097152;            // 203,948,032

    unsigned* w2b       = (unsigned*)d_ws;
    unsigned short* xT  = (unsigned short*)((char*)d_ws + off_xt);
    unsigned short* Wg  = (unsigned short*)((char*)d_ws + off_wg);
    float* biasg        = (float*)((char*)d_ws + off_bias);

    cast_w2_kernel<<<512, 256, 0, stream>>>(w2, w2b);
    if (ws_size >= need_full) {
        transpose_cast_x<<<8192, 256, 0, stream>>>(x, xT);
        wgen16_kernel<<<2048, 256, 0, stream>>>(z, w1, b1, b2, w3, b3, w4, b4,
                                                (const uint4*)w2b, Wg, biasg);
        hyperconv_apply<<<4096, 256, 0, stream>>>(xT, Wg, biasg, out);
    } else if (ws_size >= need_xt) {
        transpose_cast_x<<<8192, 256, 0, stream>>>(x, xT);
        hyperconv_mfma<true><<<2048, 256, 0, stream>>>(x, xT, z, w1, b1, b2, w3, b3, w4, b4,
                                                       (const uint4*)w2b, out);
    } else {
        hyperconv_mfma<false><<<2048, 256, 0, stream>>>(x, xT, z, w1, b1, b2, w3, b3, w4, b4,
                                                        (const uint4*)w2b, out);
    }
}

// Round 7
// 373.811 us; speedup vs baseline: 2.1800x; 2.1800x over previous
//
#include <hip/hip_runtime.h>

#define CIN   64
#define COUT  64
#define HID   32
#define ZD    128
#define KC    1024
#define SPC   64
#define TLEN  65536

typedef __attribute__((ext_vector_type(8))) short bf16x8;
typedef __attribute__((ext_vector_type(4))) float f32x4;

__device__ __forceinline__ unsigned f2bf(float f) {
    unsigned u = __float_as_uint(f);
    unsigned r = u + 0x7fffu + ((u >> 16) & 1u);
    return r >> 16;
}
__device__ __forceinline__ unsigned pk2(float a, float b) {
    return f2bf(a) | (f2bf(b) << 16);
}

// w2 [8192 r][32 h] fp32 -> w2b [8192 r][16 packed bf16x2]  (B-fragment friendly)
__global__ void cast_w2_kernel(const float* __restrict__ w2, unsigned* __restrict__ w2b) {
    int i  = blockIdx.x * 256 + threadIdx.x;   // 131072
    int r  = i >> 4;
    int hp = i & 15;
    w2b[i] = pk2(w2[r * HID + 2 * hp], w2[r * HID + 2 * hp + 1]);
}

// x [B][CIN][T] fp32 -> xT [B][T][CIN] bf16 (tiled transpose through LDS)
__global__ __launch_bounds__(256)
void transpose_cast_x(const float* __restrict__ x, unsigned short* __restrict__ xT) {
    __shared__ unsigned short s[64][66];   // stride 66 shorts: conflict-free writes
    const int blk  = blockIdx.x;           // 8192 = B * T/64
    const int b    = blk >> 10;
    const int t0   = (blk & 1023) << 6;
    const int lane = threadIdx.x & 63;
    const int wv   = threadIdx.x >> 6;
    const float* xb = x + (size_t)b * CIN * TLEN;
    #pragma unroll
    for (int cc = 0; cc < 16; ++cc) {
        int c = cc * 4 + wv;
        s[lane][c] = (unsigned short)f2bf(xb[(size_t)c * TLEN + t0 + lane]);
    }
    __syncthreads();
    unsigned short* ob = xT + ((size_t)b * TLEN + t0) * CIN;
    #pragma unroll
    for (int half = 0; half < 2; ++half) {
        int si = (half * 256 + threadIdx.x) * 8;   // short index in 64x64 tile
        int t = si >> 6, c = si & 63;              // c multiple of 8 -> 4B-aligned LDS reads
        const unsigned* sp = (const unsigned*)&s[t][c];
        uint4 v; v.x = sp[0]; v.y = sp[1]; v.z = sp[2]; v.w = sp[3];
        *(uint4*)&ob[(size_t)t * CIN + c] = v;     // fully coalesced 16B/lane
    }
}

template<bool USE_XT>
__global__ __launch_bounds__(256, 2)
void hyperconv_mfma(const float* __restrict__ x, const unsigned short* __restrict__ xT,
                    const float* __restrict__ z,
                    const float* __restrict__ w1, const float* __restrict__ b1,
                    const float* __restrict__ b2,
                    const float* __restrict__ w3, const float* __restrict__ b3,
                    const float* __restrict__ w4, const float* __restrict__ b4,
                    const uint4* __restrict__ w2b,   // [8192 r][4] uint4
                    float* __restrict__ out)
{
    __shared__ __align__(16) float s_z[4][ZD];
    __shared__ __align__(16) float s_h3[4][HID];
    __shared__ __align__(16) float s_bias[4][COUT];
    __shared__ __align__(16) short s_h1b[4][HID];
    __shared__ __align__(16) short s_wc[4][2048];   // single-buffered W chunk (16 KB)

    const int tid  = threadIdx.x;
    const int w    = tid >> 6;        // wave id == sample-in-block
    const int lane = tid & 63;
    const int l15  = lane & 15;
    const int q    = lane >> 4;
    const int n0   = blockIdx.x * 4;
    const int b    = n0 >> 10;
    const int kk0  = n0 & 1023;

    // ---- Phase A: stage z[b, :, kk0..kk0+3] ----
    #pragma unroll
    for (int i = 0; i < 2; ++i) {
        int idx = tid + i * 256;
        int g = idx >> 7, d = idx & 127;
        s_z[g][d] = z[((size_t)b * ZD + d) * KC + kk0 + g];
    }
    __syncthreads();

    // ---- Phase B: h1 (bf16) and h3 ----
    {
        int g = tid >> 6, u = tid & 63;
        const float* wrow = (u < HID) ? (w1 + u * ZD) : (w3 + (u - HID) * ZD);
        float acc = (u < HID) ? b1[u] : b3[u - HID];
        #pragma unroll
        for (int d4 = 0; d4 < ZD / 4; ++d4) {
            float4 wv = *(const float4*)(wrow + 4 * d4);
            float4 zv = *(const float4*)(&s_z[g][4 * d4]);
            acc += wv.x * zv.x + wv.y * zv.y + wv.z * zv.z + wv.w * zv.w;
        }
        acc = fmaxf(acc, 0.f);
        if (u < HID) s_h1b[g][u] = (short)f2bf(acc);
        else         s_h3[g][u - HID] = acc;
    }
    __syncthreads();

    // ---- Phase C: bias = w4@h3 + b4 (wave g computes s_bias[g]) ----
    {
        int g = tid >> 6, o = tid & 63;
        float acc = b4[o];
        #pragma unroll
        for (int h4 = 0; h4 < HID / 4; ++h4) {
            float4 wv = *(const float4*)(w4 + o * HID + 4 * h4);
            float4 hv = *(const float4*)(&s_h3[g][4 * h4]);
            acc += wv.x * hv.x + wv.y * hv.y + wv.z * hv.z + wv.w * hv.w;
        }
        s_bias[g][o] = acc;
    }

    // A-fragment for W-gen: row m holds sample m>>2 => quad q's C rows are ALL sample q
    bf16x8 afrag = *(const bf16x8*)&s_h1b[l15 >> 2][q * 8];

    // Produce one ks-chunk of W (all 4 samples) into s_wc; wave w covers ik-sub w.
    // Dependency-chain broken: all 16 loads of an ntl-group issue before any MFMA;
    // b2 added AFTER the MFMA (fp32 add, numerically identical to C-init).
    auto produce = [&](int ksr) {
        const int rb = ksr * 2048 + w * 512;
        #pragma unroll
        for (int ntl = 0; ntl < 4; ++ntl) {
            const int r0i = rb + 16 * ntl + l15;
            uint4 wf[8];
            float b2v[8];
            #pragma unroll
            for (int jj = 0; jj < 8; ++jj) {
                wf[jj]  = w2b[(r0i + 64 * jj) * 4 + q];
                b2v[jj] = b2[r0i + 64 * jj];
            }
            float cvq[8];
            #pragma unroll
            for (int jj = 0; jj < 8; ++jj) {
                f32x4 c = __builtin_amdgcn_mfma_f32_16x16x32_bf16(
                    afrag, __builtin_bit_cast(bf16x8, wf[jj]),
                    (f32x4){0.f, 0.f, 0.f, 0.f}, 0, 0, 0);
                cvq[jj] = c[0] + b2v[jj];   // rows 4q..4q+3 identical (all sample q)
            }
            uint4 res;
            res.x = pk2(cvq[0], cvq[1]);
            res.y = pk2(cvq[2], cvq[3]);
            res.z = pk2(cvq[4], cvq[5]);
            res.w = pk2(cvq[6], cvq[7]);
            *(uint4*)&s_wc[q][w * 512 + (16 * ntl + l15) * 8] = res;
        }
    };

    produce(0);
    __syncthreads();

    // ---- Main loop: consume chunk ks; then produce chunk ks+1 (single buffer) ----
    const int t0 = (kk0 + w) * SPC;
    const float* xb = x + (size_t)b * CIN * TLEN;
    const unsigned short* xtb = xT + (size_t)b * TLEN * CIN;

    f32x4 acc[4][4];
    #pragma unroll
    for (int i = 0; i < 4; ++i)
        #pragma unroll
        for (int j = 0; j < 4; ++j) acc[i][j] = (f32x4){0.f, 0.f, 0.f, 0.f};

    #pragma unroll
    for (int ks = 0; ks < 4; ++ks) {
        // B fragments from x
        const int koff = (ks >= 2) ? -1 : 0;   // ik>=64 -> x[t-1]
        const int c0 = (ks & 1) * 32 + 8 * q;
        bf16x8 bfr[4];
        if (USE_XT) {
            #pragma unroll
            for (int st = 0; st < 4; ++st) {
                int t = t0 + 16 * st + l15 + koff;
                uint4 p = (uint4){0u, 0u, 0u, 0u};
                if (t >= 0) p = *(const uint4*)&xtb[(size_t)t * CIN + c0];
                bfr[st] = __builtin_bit_cast(bf16x8, p);
            }
        } else {
            #pragma unroll
            for (int st = 0; st < 4; ++st) {
                int t = t0 + 16 * st + l15 + koff;
                int tc = t < 0 ? 0 : t;
                float v[8];
                #pragma unroll
                for (int j = 0; j < 8; ++j)
                    v[j] = xb[(size_t)(c0 + j) * TLEN + tc];
                if (t < 0) {
                    #pragma unroll
                    for (int j = 0; j < 8; ++j) v[j] = 0.f;
                }
                uint4 p;
                p.x = pk2(v[0], v[1]); p.y = pk2(v[2], v[3]);
                p.z = pk2(v[4], v[5]); p.w = pk2(v[6], v[7]);
                bfr[st] = __builtin_bit_cast(bf16x8, p);
            }
        }

        // A fragments from current W chunk, one at a time
        #pragma unroll
        for (int ot = 0; ot < 4; ++ot) {
            bf16x8 afr = *(const bf16x8*)&s_wc[w][q * 512 + (16 * ot + l15) * 8];
            #pragma unroll
            for (int st = 0; st < 4; ++st)
                acc[ot][st] = __builtin_amdgcn_mfma_f32_16x16x32_bf16(
                    afr, bfr[st], acc[ot][st], 0, 0, 0);
        }

        // single buffer: drain reads, overwrite with next chunk, publish
        if (ks < 3) {
            __syncthreads();
            produce(ks + 1);
            __syncthreads();
        }
    }

    // ---- Epilogue: add bias, store (row=o, col=s; 16 consecutive t per quad) ----
    float* ob = out + (size_t)b * COUT * TLEN;
    #pragma unroll
    for (int ot = 0; ot < 4; ++ot) {
        f32x4 bv = *(const f32x4*)&s_bias[w][16 * ot + 4 * q];
        #pragma unroll
        for (int st = 0; st < 4; ++st) {
            int t = t0 + 16 * st + l15;
            #pragma unroll
            for (int reg = 0; reg < 4; ++reg)
                ob[(size_t)(16 * ot + 4 * q + reg) * TLEN + t] = acc[ot][st][reg] + bv[reg];
        }
    }
}

extern "C" void kernel_launch(void* const* d_in, const int* in_sizes, int n_in,
                              void* d_out, int out_size, void* d_ws, size_t ws_size,
                              hipStream_t stream) {
    const float* x  = (const float*)d_in[0];
    const float* z  = (const float*)d_in[1];
    const float* w1 = (const float*)d_in[2];
    const float* b1 = (const float*)d_in[3];
    const float* w2 = (const float*)d_in[4];
    const float* b2 = (const float*)d_in[5];
    const float* w3 = (const float*)d_in[6];
    const float* b3 = (const float*)d_in[7];
    const float* w4 = (const float*)d_in[8];
    const float* b4 = (const float*)d_in[9];
    float* out = (float*)d_out;

    unsigned* w2b = (unsigned*)d_ws;                                   // 512 KB
    unsigned short* xT = (unsigned short*)((char*)d_ws + 524288);      // 64 MB bf16 x^T
    const size_t need_xt = 524288ull + (size_t)8 * TLEN * CIN * 2;     // 67,633,152 B

    cast_w2_kernel<<<512, 256, 0, stream>>>(w2, w2b);
    if (ws_size >= need_xt) {
        transpose_cast_x<<<8192, 256, 0, stream>>>(x, xT);
        hyperconv_mfma<true><<<2048, 256, 0, stream>>>(x, xT, z, w1, b1, b2, w3, b3, w4, b4,
                                                       (const uint4*)w2b, out);
    } else {
        hyperconv_mfma<false><<<2048, 256, 0, stream>>>(x, xT, z, w1, b1, b2, w3, b3, w4, b4,
                                                        (const uint4*)w2b, out);
    }
}